// Round 1
// baseline (513.953 us; speedup 1.0000x reference)
//
#include <hip/hip_runtime.h>

#define DIM   768
#define NCLS  1024
#define INST  64
#define MOM   0.8f

// Wave64 sum via DPP (VALU pipe only — no ds_bpermute round trips), result
// broadcast to all lanes through an SGPR readlane.
// Sequence: row_shr 1/2/4/8 (lane15 of each 16-lane row = row total),
// row_bcast15 into rows 1,3, row_bcast31 into rows 2,3 -> lane63 = wave total.
__device__ __forceinline__ float wave_sum_bcast(float v) {
#define DPPA(ctrl, rmask)                                                  \
    v += __int_as_float(__builtin_amdgcn_update_dpp(                        \
        0, __float_as_int(v), ctrl, rmask, 0xf, true))
    DPPA(0x111, 0xf);   // row_shr:1
    DPPA(0x112, 0xf);   // row_shr:2
    DPPA(0x114, 0xf);   // row_shr:4
    DPPA(0x118, 0xf);   // row_shr:8
    DPPA(0x142, 0xa);   // row_bcast15 -> rows 1,3
    DPPA(0x143, 0xc);   // row_bcast31 -> rows 2,3
#undef DPPA
    return __int_as_float(__builtin_amdgcn_readlane(__float_as_int(v), 63));
}

// One modality for one class: 8 waves x 8 rows, depth-1 prefetch pipeline,
// per-row DPP normalize-reduce, per-wave sums staged in LDS, then the
// per-class EMA/MSE term accumulated into tacc.
__device__ __forceinline__ void do_modality(
    const float4* __restrict__ base,    // this class's 64 feature rows
    const float*  __restrict__ centc,   // this class's center row
    float* __restrict__ lds_sum,        // [8][DIM]
    const int tid, const int lane, const int wave,
    float& tacc)
{
    float4 a0 = make_float4(0.f, 0.f, 0.f, 0.f);
    float4 a1 = make_float4(0.f, 0.f, 0.f, 0.f);
    float4 a2 = make_float4(0.f, 0.f, 0.f, 0.f);

    auto normacc = [&](const float4 x, const float4 y, const float4 z) {
        float s = x.x * x.x + x.y * x.y + x.z * x.z + x.w * x.w
                + y.x * y.x + y.y * y.y + y.z * y.z + y.w * y.w
                + z.x * z.x + z.y * z.y + z.z * z.z + z.w * z.w;
        s = wave_sum_bcast(s);
        const float inv = 1.0f / fmaxf(sqrtf(s), 1e-12f);  // F.normalize eps
        a0.x = fmaf(x.x, inv, a0.x); a0.y = fmaf(x.y, inv, a0.y);
        a0.z = fmaf(x.z, inv, a0.z); a0.w = fmaf(x.w, inv, a0.w);
        a1.x = fmaf(y.x, inv, a1.x); a1.y = fmaf(y.y, inv, a1.y);
        a1.z = fmaf(y.z, inv, a1.z); a1.w = fmaf(y.w, inv, a1.w);
        a2.x = fmaf(z.x, inv, a2.x); a2.y = fmaf(z.y, inv, a2.y);
        a2.z = fmaf(z.z, inv, a2.z); a2.w = fmaf(z.w, inv, a2.w);
    };

    // wave w owns rows w, w+8, ..., w+56.  Prefetch row j+1 while reducing
    // row j so 3 wave-loads stay outstanding through the reduce chain.
    const float4* rp = base + (size_t)wave * (DIM / 4);
    float4 x0 = rp[lane], y0 = rp[lane + 64], z0 = rp[lane + 128];
#pragma unroll 1
    for (int j = 0; j < 7; ++j) {
        rp += 8 * (DIM / 4);
        const float4 x1 = rp[lane];
        const float4 y1 = rp[lane + 64];
        const float4 z1 = rp[lane + 128];
        normacc(x0, y0, z0);
        x0 = x1; y0 = y1; z0 = z1;
    }
    normacc(x0, y0, z0);

    // stage per-wave normalized sums
    float4* dst = (float4*)(lds_sum + (size_t)wave * DIM);
    dst[lane]       = a0;
    dst[lane + 64]  = a1;
    dst[lane + 128] = a2;
    __syncthreads();

    // per-class term: INST*||c||^2 - 2*c.S   (the +INST is folded in at the end)
    {
        const int d = tid;           // 512 threads cover d = 0..511
        float S = 0.f;
#pragma unroll
        for (int w = 0; w < 8; ++w) S += lds_sum[w * DIM + d];
        const float c = fmaf(MOM / (float)INST, S, (1.0f - MOM) * centc[d]);
        tacc = fmaf((float)INST * c, c, tacc);
        tacc = fmaf(-2.0f * c, S, tacc);
    }
    if (tid < DIM - 512) {           // 256 threads cover d = 512..767
        const int d = tid + 512;
        float S = 0.f;
#pragma unroll
        for (int w = 0; w < 8; ++w) S += lds_sum[w * DIM + d];
        const float c = fmaf(MOM / (float)INST, S, (1.0f - MOM) * centc[d]);
        tacc = fmaf((float)INST * c, c, tacc);
        tacc = fmaf(-2.0f * c, S, tacc);
    }
    __syncthreads();                 // LDS reused by the next modality
}

// grid: NCLS blocks of 512 threads.  Block b handles class b for ALL three
// modalities -> 1024 blocks / 256 CUs = exactly 4 resident blocks per CU
// (32 waves/CU), uniform work, no second scheduling generation, no tail.
__global__ __launch_bounds__(512, 8) void fused_class_kernel(
    const float* __restrict__ f0, const float* __restrict__ f1, const float* __restrict__ f2,
    const float* __restrict__ c0, const float* __restrict__ c1, const float* __restrict__ c2,
    const int*   __restrict__ label,
    float*       __restrict__ partial)
{
    const int blk  = blockIdx.x;
    const int tid  = threadIdx.x;
    const int lane = tid & 63;
    const int wave = tid >> 6;

    __shared__ float lds_sum[8 * DIM];   // 24.6 KB -> 4 blocks/CU fit easily
    __shared__ float lds_red[8];

    const int    cls     = label[blk * INST];   // all 64 rows share this class
    const size_t rowbase = (size_t)blk * INST * (DIM / 4);

    float tacc = 0.f;
    do_modality((const float4*)f0 + rowbase, c0 + (size_t)cls * DIM,
                lds_sum, tid, lane, wave, tacc);
    do_modality((const float4*)f1 + rowbase, c1 + (size_t)cls * DIM,
                lds_sum, tid, lane, wave, tacc);
    do_modality((const float4*)f2 + rowbase, c2 + (size_t)cls * DIM,
                lds_sum, tid, lane, wave, tacc);

    const float t = wave_sum_bcast(tacc);
    if (lane == 0) lds_red[wave] = t;
    __syncthreads();
    if (tid == 0) {
        float s = 0.f;
#pragma unroll
        for (int w = 0; w < 8; ++w) s += lds_red[w];
        partial[blk] = s;
    }
}

// single block, 1024 threads: reduce 1024 per-class partials -> scalar loss
__global__ __launch_bounds__(1024) void reduce_kernel(
    const float* __restrict__ partial, float* __restrict__ out)
{
    __shared__ float lds[16];
    const int tid = threadIdx.x;
    float t = partial[tid];
    t = wave_sum_bcast(t);
    if ((tid & 63) == 0) lds[tid >> 6] = t;
    __syncthreads();
    if (tid == 0) {
        float s = 0.f;
#pragma unroll
        for (int i = 0; i < 16; ++i) s += lds[i];
        const float B = (float)(NCLS * INST);
        // + 3*B accounts for Sum ||x_i||^2 = B per modality; ALPHA = 1
        out[0] = (s + 3.0f * B) / (B * (float)DIM);
    }
}

extern "C" void kernel_launch(void* const* d_in, const int* in_sizes, int n_in,
                              void* d_out, int out_size, void* d_ws, size_t ws_size,
                              hipStream_t stream)
{
    const float* f0 = (const float*)d_in[0];  // RGB_feat  [65536,768]
    const float* f1 = (const float*)d_in[1];  // NIR_feat
    const float* f2 = (const float*)d_in[2];  // TIR_feat
    const float* c0 = (const float*)d_in[3];  // RGB_centers [1024,768]
    const float* c1 = (const float*)d_in[4];  // NIR_centers
    const float* c2 = (const float*)d_in[5];  // TIR_centers
    const int*   lb = (const int*)d_in[6];    // label_ [65536]
    // d_in[7] = epoch (unused by the reference output)

    float* partial = (float*)d_ws;            // 1024 floats, fully written

    fused_class_kernel<<<NCLS, 512, 0, stream>>>(f0, f1, f2, c0, c1, c2, lb, partial);
    reduce_kernel<<<1, 1024, 0, stream>>>(partial, (float*)d_out);
}